// Round 1
// baseline (731.837 us; speedup 1.0000x reference)
//
#include <hip/hip_runtime.h>
#include <stdint.h>

#define N_PROP 100000
#define N_CLS  91
#define NFG    90          // foreground classes
#define TOPK   1000
#define NWORD  16          // 1000 bits -> 16 u64 words
#define CAND_MAX 2048
#define DETS   100
#define SCORE_THRESH 0.05f
#define BBOX_CLIP 4.135166556742356f   // log(1000/16)

__device__ __forceinline__ float clampf(float v, float lo, float hi) {
    return fminf(fmaxf(v, lo), hi);
}

// ---------------------------------------------------------------------------
// Kernel 1: softmax over 91 classes, write transposed scores_t[90][N_PROP]
// (foreground classes only; scores_t[c][i] = softmax(logits[i])[c+1])
// ---------------------------------------------------------------------------
__global__ __launch_bounds__(256) void softmax_kernel(
    const float* __restrict__ logits, float* __restrict__ scores_t) {
    int row = blockIdx.x * blockDim.x + threadIdx.x;
    if (row >= N_PROP) return;
    const float* lrow = logits + (size_t)row * N_CLS;
    float m = -INFINITY;
    for (int c = 0; c < N_CLS; ++c) m = fmaxf(m, lrow[c]);
    float sum = 0.f;
    for (int c = 0; c < N_CLS; ++c) sum += expf(lrow[c] - m);
    for (int c = 1; c < N_CLS; ++c) {
        float s = expf(lrow[c] - m) / sum;
        scores_t[(size_t)(c - 1) * N_PROP + row] = s;  // coalesced per-c
    }
}

// ---------------------------------------------------------------------------
// Kernel 2: per-class exact top-1000 (desc, stable by index) via 2-level
// radix histogram select + bitonic sort. One block (1024 thr) per class.
// Positive float bits are order-isomorphic to their values.
// ---------------------------------------------------------------------------
__global__ __launch_bounds__(1024) void select_topk_kernel(
    const float* __restrict__ scores_t,
    float* __restrict__ sel_score, int* __restrict__ sel_idx) {
    const int c = blockIdx.x;
    const int tid = threadIdx.x;
    const float* sc = scores_t + (size_t)c * N_PROP;

    __shared__ unsigned int hist[8][1024];     // 8 copies to break contention
    __shared__ unsigned long long cand[CAND_MAX];
    __shared__ unsigned int s_cnt, s_b1, s_above, s_b2;

    for (int i = tid; i < 8 * 1024; i += 1024) (&hist[0][0])[i] = 0u;
    if (tid == 0) s_cnt = 0u;
    __syncthreads();

    // level-1 histogram on bits>>20 (scores in (0,1) => bins < 1024)
    for (int i = tid; i < N_PROP; i += 1024) {
        unsigned int bits = __float_as_uint(sc[i]);
        atomicAdd(&hist[tid & 7][bits >> 20], 1u);
    }
    __syncthreads();
    unsigned int merged = 0;
    for (int r = 0; r < 8; ++r) merged += hist[r][tid];
    __syncthreads();
    hist[0][tid] = merged;
    __syncthreads();
    // suffix scan: hist[0][t] = count of elements in bins >= t
    for (int off = 1; off < 1024; off <<= 1) {
        unsigned int v = (tid + off < 1024) ? hist[0][tid + off] : 0u;
        __syncthreads();
        hist[0][tid] += v;
        __syncthreads();
    }
    if (hist[0][tid] >= TOPK && (tid == 1023 || hist[0][tid + 1] < TOPK)) {
        s_b1 = (unsigned)tid;
        s_above = (tid == 1023) ? 0u : hist[0][tid + 1];
    }
    __syncthreads();
    const unsigned int b1 = s_b1, above = s_above;
    const unsigned int need2 = TOPK - above;
    __syncthreads();
    hist[0][tid] = 0u;
    __syncthreads();
    // level-2 histogram (bits 19..10) within bin b1
    for (int i = tid; i < N_PROP; i += 1024) {
        unsigned int bits = __float_as_uint(sc[i]);
        if ((bits >> 20) == b1) atomicAdd(&hist[0][(bits >> 10) & 1023u], 1u);
    }
    __syncthreads();
    for (int off = 1; off < 1024; off <<= 1) {
        unsigned int v = (tid + off < 1024) ? hist[0][tid + off] : 0u;
        __syncthreads();
        hist[0][tid] += v;
        __syncthreads();
    }
    if (hist[0][tid] >= need2 && (tid == 1023 || hist[0][tid + 1] < need2))
        s_b2 = (unsigned)tid;
    __syncthreads();
    const unsigned int thresh22 = (b1 << 10) | s_b2;
    // compact all elements with top-22 bits >= threshold (count in [1000, ~1010])
    for (int i = tid; i < N_PROP; i += 1024) {
        unsigned int bits = __float_as_uint(sc[i]);
        if ((bits >> 10) >= thresh22) {
            unsigned int pos = atomicAdd(&s_cnt, 1u);
            if (pos < CAND_MAX)
                cand[pos] = ((unsigned long long)bits << 32) |
                            (unsigned int)(~(unsigned int)i);
        }
    }
    __syncthreads();
    unsigned int cnt = s_cnt < CAND_MAX ? s_cnt : CAND_MAX;
    for (int i = tid; i < CAND_MAX; i += 1024)
        if ((unsigned)i >= cnt) cand[i] = 0ull;
    __syncthreads();
    // bitonic sort 2048 keys, descending: (score_bits desc, idx asc)
    for (unsigned int k = 2; k <= CAND_MAX; k <<= 1) {
        for (unsigned int j = k >> 1; j > 0; j >>= 1) {
            for (unsigned int i = tid; i < CAND_MAX; i += 1024) {
                unsigned int ixj = i ^ j;
                if (ixj > i) {
                    unsigned long long a = cand[i], b = cand[ixj];
                    bool desc = ((i & k) == 0);
                    if (desc ? (a < b) : (a > b)) { cand[i] = b; cand[ixj] = a; }
                }
            }
            __syncthreads();
        }
    }
    if (tid < TOPK) {
        unsigned long long kk = cand[tid];
        sel_score[c * TOPK + tid] = __uint_as_float((unsigned int)(kk >> 32));
        sel_idx[c * TOPK + tid] = (int)(~(unsigned int)(kk & 0xFFFFFFFFull));
    }
}

// ---------------------------------------------------------------------------
// Kernel 3: decode + clip the 90k selected boxes only
// ---------------------------------------------------------------------------
__global__ __launch_bounds__(256) void decode_kernel(
    const float* __restrict__ box_reg, const float* __restrict__ proposals,
    const int* __restrict__ sel_idx, float* __restrict__ sel_box) {
#pragma clang fp contract(off)
    int t = blockIdx.x * blockDim.x + threadIdx.x;
    if (t >= NFG * TOPK) return;
    int c = t / TOPK;           // fg class index, label = c+1
    int i = sel_idx[t];
    float x1 = proposals[i * 4 + 0], y1 = proposals[i * 4 + 1];
    float x2 = proposals[i * 4 + 2], y2 = proposals[i * 4 + 3];
    float w = x2 - x1 + 1.0f, h = y2 - y1 + 1.0f;
    float cx = x1 + 0.5f * w, cy = y1 + 0.5f * h;
    const float* d = box_reg + (size_t)i * (N_CLS * 4) + (size_t)(c + 1) * 4;
    float dx = d[0] / 10.0f, dy = d[1] / 10.0f;
    float dw = fminf(d[2] / 5.0f, BBOX_CLIP);
    float dh = fminf(d[3] / 5.0f, BBOX_CLIP);
    float pcx = dx * w + cx, pcy = dy * h + cy;
    float pw = expf(dw) * w, ph = expf(dh) * h;
    float ox1 = clampf(pcx - 0.5f * pw, 0.f, 1332.f);
    float oy1 = clampf(pcy - 0.5f * ph, 0.f, 799.f);
    float ox2 = clampf(pcx + 0.5f * pw - 1.0f, 0.f, 1332.f);
    float oy2 = clampf(pcy + 0.5f * ph - 1.0f, 0.f, 799.f);
    float4 o = make_float4(ox1, oy1, ox2, oy2);
    ((float4*)sel_box)[t] = o;
}

// ---------------------------------------------------------------------------
// Kernel 4a: suppression bitmask matrix. mask[c][i] bit j set iff
// j>i && IoU(box_i,box_j) > 0.5. grid (90 classes x 8 row-chunks of 125).
// ---------------------------------------------------------------------------
__global__ __launch_bounds__(256) void mask_kernel(
    const float* __restrict__ sel_box, unsigned long long* __restrict__ mask) {
#pragma clang fp contract(off)
    const int c = blockIdx.x;
    const int chunk = blockIdx.y;
    __shared__ float4 box[TOPK];
    __shared__ float  area[TOPK];
    for (int t = threadIdx.x; t < TOPK; t += 256) {
        float4 b = ((const float4*)sel_box)[c * TOPK + t];
        box[t] = b;
        area[t] = (b.z - b.x + 1.0f) * (b.w - b.y + 1.0f);
    }
    __syncthreads();
    const int r0 = chunk * 125;
    for (int task = threadIdx.x; task < 125 * NWORD; task += 256) {
        int r = r0 + task / NWORD;
        int w = task % NWORD;
        unsigned long long bits = 0ull;
        int jbase = w * 64;
        if (jbase + 63 > r) {
            float4 br = box[r];
            float ar = area[r];
            int jstart = (jbase > r + 1) ? jbase : r + 1;
            int jend = (jbase + 64 < TOPK) ? jbase + 64 : TOPK;
            for (int j = jstart; j < jend; ++j) {
                float4 bj = box[j];
                float ltx = fmaxf(br.x, bj.x), lty = fmaxf(br.y, bj.y);
                float rbx = fminf(br.z, bj.z), rby = fminf(br.w, bj.w);
                float iw = fmaxf(rbx - ltx + 1.0f, 0.f);
                float ih = fmaxf(rby - lty + 1.0f, 0.f);
                float inter = iw * ih;
                float iou = inter / (ar + area[j] - inter);
                if (iou > 0.5f) bits |= 1ull << (j - jbase);
            }
        }
        mask[((size_t)c * TOPK + r) * NWORD + w] = bits;
    }
}

// ---------------------------------------------------------------------------
// Kernel 4b: serial greedy sweep over the bitmask, one wave per class.
// Lane l (<16) owns keep-word l. Mask rows prefetched depth-8 in registers.
// Writes -1.0f into sel_score for suppressed / below-threshold entries.
// ---------------------------------------------------------------------------
__global__ __launch_bounds__(64) void nms_reduce_kernel(
    const unsigned long long* __restrict__ mask, float* __restrict__ sel_score) {
    const int c = blockIdx.x;
    const int lane = threadIdx.x;
    __shared__ unsigned long long keep_lds[NWORD];

    // init keep bits from score threshold (coalesced, via ballot)
    unsigned long long keep = 0ull;
    for (int w = 0; w < NWORD; ++w) {
        int j = w * 64 + lane;
        float s = (j < TOPK) ? sel_score[c * TOPK + j] : -1.0f;
        unsigned long long m = __ballot(s > SCORE_THRESH);
        if (lane == w) keep = m;
    }

    const unsigned long long* mrow = mask + (size_t)c * TOPK * NWORD;
    const int w = (lane < NWORD) ? lane : 0;
    unsigned long long pre[8];
#pragma unroll
    for (int d = 0; d < 8; ++d) pre[d] = mrow[(size_t)d * NWORD + w];

    for (int i = 0; i < TOPK; i += 8) {
#pragma unroll
        for (int d = 0; d < 8; ++d) {
            int ii = i + d;
            unsigned long long row = pre[d];
            pre[d] = (ii + 8 < TOPK) ? mrow[(size_t)(ii + 8) * NWORD + w] : 0ull;
            unsigned long long kw = __shfl(keep, ii >> 6);
            if ((kw >> (ii & 63)) & 1ull) keep &= ~row;
        }
    }
    if (lane < NWORD) keep_lds[lane] = keep;
    __syncthreads();
    for (int j = lane; j < TOPK; j += 64) {
        bool k = (keep_lds[j >> 6] >> (j & 63)) & 1ull;
        if (!k) sel_score[c * TOPK + j] = -1.0f;
    }
}

// ---------------------------------------------------------------------------
// Kernel 5: global top-100 of the 90000 candidate scores (stable desc),
// gather boxes/scores/labels into d_out = [boxes 400 | scores 100 | labels 100]
// ---------------------------------------------------------------------------
__global__ __launch_bounds__(1024) void final_topk_kernel(
    const float* __restrict__ sel_score, const float* __restrict__ sel_box,
    float* __restrict__ out) {
    const int tid = threadIdx.x;
    const int M = NFG * TOPK;
    __shared__ unsigned int hist[8][1024];
    __shared__ unsigned long long cand[CAND_MAX];
    __shared__ unsigned int s_cnt, s_b1, s_above, s_b2;

    // count positives (so we can exclude the massive -1.0 duplicate bin)
    unsigned int local = 0;
    for (int i = tid; i < M; i += 1024) local += (sel_score[i] > SCORE_THRESH);
    hist[0][tid] = local;
    __syncthreads();
    for (int off = 512; off > 0; off >>= 1) {
        if (tid < off) hist[0][tid] += hist[0][tid + off];
        __syncthreads();
    }
    const bool usefilter = hist[0][0] >= DETS;
    __syncthreads();
    for (int i = tid; i < 8 * 1024; i += 1024) (&hist[0][0])[i] = 0u;
    if (tid == 0) s_cnt = 0u;
    __syncthreads();

    // level-1 histogram on orderable key >> 22
    for (int i = tid; i < M; i += 1024) {
        float s = sel_score[i];
        if (usefilter && !(s > SCORE_THRESH)) continue;
        unsigned int u = __float_as_uint(s);
        unsigned int o = (u & 0x80000000u) ? ~u : (u | 0x80000000u);
        atomicAdd(&hist[tid & 7][o >> 22], 1u);
    }
    __syncthreads();
    unsigned int merged = 0;
    for (int r = 0; r < 8; ++r) merged += hist[r][tid];
    __syncthreads();
    hist[0][tid] = merged;
    __syncthreads();
    for (int off = 1; off < 1024; off <<= 1) {
        unsigned int v = (tid + off < 1024) ? hist[0][tid + off] : 0u;
        __syncthreads();
        hist[0][tid] += v;
        __syncthreads();
    }
    if (hist[0][tid] >= DETS && (tid == 1023 || hist[0][tid + 1] < DETS)) {
        s_b1 = (unsigned)tid;
        s_above = (tid == 1023) ? 0u : hist[0][tid + 1];
    }
    __syncthreads();
    const unsigned int b1 = s_b1, above = s_above;
    const unsigned int need2 = DETS - above;
    __syncthreads();
    hist[0][tid] = 0u;
    __syncthreads();
    for (int i = tid; i < M; i += 1024) {
        float s = sel_score[i];
        if (usefilter && !(s > SCORE_THRESH)) continue;
        unsigned int u = __float_as_uint(s);
        unsigned int o = (u & 0x80000000u) ? ~u : (u | 0x80000000u);
        if ((o >> 22) == b1) atomicAdd(&hist[0][(o >> 12) & 1023u], 1u);
    }
    __syncthreads();
    for (int off = 1; off < 1024; off <<= 1) {
        unsigned int v = (tid + off < 1024) ? hist[0][tid + off] : 0u;
        __syncthreads();
        hist[0][tid] += v;
        __syncthreads();
    }
    if (hist[0][tid] >= need2 && (tid == 1023 || hist[0][tid + 1] < need2))
        s_b2 = (unsigned)tid;
    __syncthreads();
    const unsigned int thresh20 = (b1 << 10) | s_b2;
    for (int i = tid; i < M; i += 1024) {
        float s = sel_score[i];
        if (usefilter && !(s > SCORE_THRESH)) continue;
        unsigned int u = __float_as_uint(s);
        unsigned int o = (u & 0x80000000u) ? ~u : (u | 0x80000000u);
        if ((o >> 12) >= thresh20) {
            unsigned int pos = atomicAdd(&s_cnt, 1u);
            if (pos < CAND_MAX)
                cand[pos] = ((unsigned long long)o << 32) |
                            (unsigned int)(~(unsigned int)i);
        }
    }
    __syncthreads();
    unsigned int cnt = s_cnt < CAND_MAX ? s_cnt : CAND_MAX;
    for (int i = tid; i < CAND_MAX; i += 1024)
        if ((unsigned)i >= cnt) cand[i] = 0ull;
    __syncthreads();
    for (unsigned int k = 2; k <= CAND_MAX; k <<= 1) {
        for (unsigned int j = k >> 1; j > 0; j >>= 1) {
            for (unsigned int i = tid; i < CAND_MAX; i += 1024) {
                unsigned int ixj = i ^ j;
                if (ixj > i) {
                    unsigned long long a = cand[i], b = cand[ixj];
                    bool desc = ((i & k) == 0);
                    if (desc ? (a < b) : (a > b)) { cand[i] = b; cand[ixj] = a; }
                }
            }
            __syncthreads();
        }
    }
    if (tid < DETS) {
        unsigned long long kk = cand[tid];
        unsigned int flat = ~(unsigned int)(kk & 0xFFFFFFFFull);
        float s = sel_score[flat];
        float4 b = ((const float4*)sel_box)[flat];
        out[tid * 4 + 0] = b.x;
        out[tid * 4 + 1] = b.y;
        out[tid * 4 + 2] = b.z;
        out[tid * 4 + 3] = b.w;
        out[400 + tid] = s;
        out[500 + tid] = (float)(flat / TOPK + 1);   // label
    }
}

// ---------------------------------------------------------------------------
extern "C" void kernel_launch(void* const* d_in, const int* in_sizes, int n_in,
                              void* d_out, int out_size, void* d_ws, size_t ws_size,
                              hipStream_t stream) {
    const float* logits    = (const float*)d_in[0];   // [100000, 91]
    const float* box_reg   = (const float*)d_in[1];   // [100000, 364]
    const float* proposals = (const float*)d_in[2];   // [100000, 4]
    float* out = (float*)d_out;                       // 600 floats

    char* ws = (char*)d_ws;
    size_t off = 0;
    auto walloc = [&](size_t bytes) -> char* {
        char* p = ws + off;
        off += (bytes + 255) & ~(size_t)255;
        return p;
    };
    float* scores_t = (float*)walloc((size_t)NFG * N_PROP * sizeof(float)); // 36 MB
    float* sel_score = (float*)walloc((size_t)NFG * TOPK * sizeof(float));
    int*   sel_idx   = (int*)walloc((size_t)NFG * TOPK * sizeof(int));
    float* sel_box   = (float*)walloc((size_t)NFG * TOPK * 4 * sizeof(float));
    unsigned long long* mask =
        (unsigned long long*)walloc((size_t)NFG * TOPK * NWORD * 8); // 11.5 MB
    (void)ws_size; (void)in_sizes; (void)n_in; (void)out_size;

    softmax_kernel<<<(N_PROP + 255) / 256, 256, 0, stream>>>(logits, scores_t);
    select_topk_kernel<<<NFG, 1024, 0, stream>>>(scores_t, sel_score, sel_idx);
    decode_kernel<<<(NFG * TOPK + 255) / 256, 256, 0, stream>>>(
        box_reg, proposals, sel_idx, sel_box);
    mask_kernel<<<dim3(NFG, 8), 256, 0, stream>>>(sel_box, mask);
    nms_reduce_kernel<<<NFG, 64, 0, stream>>>(mask, sel_score);
    final_topk_kernel<<<1, 1024, 0, stream>>>(sel_score, sel_box, out);
}